// Round 9
// baseline (369.237 us; speedup 1.0000x reference)
//
#include <hip/hip_runtime.h>
#include <hip/hip_bf16.h>
#include <math.h>

#define N_USER 100000
#define N_ITEM 50000
#define NNODE  150000   // N_USER + N_ITEM
#define DIM    64
#define NEDGE  2000000
#define BSZ    8192
#define NTGT   (3*BSZ)
#define CB     586      // ceil(NNODE/256) coarse buckets
#define NB     512      // edge chunks
#define CH     ((NEDGE + NB - 1)/NB)   // 3907
#define LBLK   2048
#define PREPB  (NNODE*32/256)   // 18750 prep blocks (u32 outputs)
#define CAP    5120     // k_csr per-bucket LDS capacity
#define DB     128      // degree-sort bins

typedef float v2f __attribute__((ext_vector_type(2)));

__device__ __forceinline__ float logsigf(float x){
    return fminf(x, 0.f) - log1pf(expf(-fabsf(x)));
}
__device__ __forceinline__ float softplusf(float x){
    return fmaxf(x, 0.f) + log1pf(expf(-fabsf(x)));
}
__device__ __forceinline__ v2f fp8x2_to_f32(unsigned short u){
    return __builtin_amdgcn_cvt_pk_f32_fp8((int)u, false);
}
__device__ __forceinline__ unsigned short f32_to_fp8x2(float a, float b){
    return (unsigned short)__builtin_amdgcn_cvt_pk_fp8_f32(a, b, 0, false);
}
__device__ __forceinline__ unsigned rfl(unsigned v){
    return (unsigned)__builtin_amdgcn_readfirstlane((int)v);
}

// exclusive scan of arr[CB] in LDS with 256 threads (each owns 3 slots)
__device__ __forceinline__ void scanCB(unsigned* arr, unsigned* tmp){
    int t = threadIdx.x;
    int base = 3*t;
    unsigned a0=0,a1=0,a2=0;
    if(base   < CB) a0 = arr[base];
    if(base+1 < CB) a1 = arr[base+1];
    if(base+2 < CB) a2 = arr[base+2];
    unsigned s = a0+a1+a2;
    tmp[t]=s; __syncthreads();
    for(int off=1; off<256; off<<=1){
        unsigned v = (t>=off)? tmp[t-off] : 0u;
        __syncthreads();
        tmp[t] += v;
        __syncthreads();
    }
    unsigned excl = tmp[t]-s;
    if(base   < CB) arr[base]   = excl;
    if(base+1 < CB) arr[base+1] = excl+a0;
    if(base+2 < CB) arr[base+2] = excl+a0+a1;
    __syncthreads();
}

// ==== fused: coarse histograms ([chunk][bin] layout!) + fp8 prep + misc ==
__global__ __launch_bounds__(256) void k_hist(const int* __restrict__ src, const int* __restrict__ dst,
                       unsigned* __restrict__ histD, unsigned* __restrict__ histS,
                       const float2* __restrict__ ei, const float2* __restrict__ ep,
                       unsigned* __restrict__ hC32,
                       const unsigned char* __restrict__ mask8, unsigned* __restrict__ mflag,
                       unsigned* __restrict__ dhist, unsigned* __restrict__ dcur){
    if(blockIdx.x >= NB){
        if(blockIdx.x == NB + PREPB){
            __shared__ int any;
            if(threadIdx.x==0) any=0;
            if(threadIdx.x < DB){ dhist[threadIdx.x]=0u; dcur[threadIdx.x]=0u; }
            __syncthreads();
            for(int i=threadIdx.x;i<BSZ;i+=256){ if((i&3) && mask8[i]) any=1; }
            __syncthreads();
            if(threadIdx.x==0) *mflag = (any!=0) ? 1u : 0u;
            return;
        }
        int idx = (blockIdx.x - NB)*256 + threadIdx.x;
        int n = idx>>5, c = idx&31;
        float2 va, vb;
        if(c<16){ va = ei[(size_t)n*32 + 2*c]; vb = ei[(size_t)n*32 + 2*c+1]; }
        else    { va = ep[(size_t)n*32 + 2*c-32]; vb = ep[(size_t)n*32 + 2*c-31]; }
        int d = __builtin_amdgcn_cvt_pk_fp8_f32(va.x, va.y, 0, false);
        d = __builtin_amdgcn_cvt_pk_fp8_f32(vb.x, vb.y, d, true);
        hC32[(size_t)n*32 + c] = (unsigned)d;
        return;
    }
    __shared__ unsigned hD[CB], hS[CB];
    for(int i=threadIdx.x;i<CB;i+=256){ hD[i]=0; hS[i]=0; }
    __syncthreads();
    int lo = blockIdx.x*CH, hi = min(lo+CH, NEDGE);
    for(int e=lo+threadIdx.x; e<hi; e+=256){
        atomicAdd(&hS[src[e]>>8],1u);
        atomicAdd(&hD[dst[e]>>8],1u);
    }
    __syncthreads();
    for(int i=threadIdx.x;i<CB;i+=256){          // contiguous full-line writes
        histD[(size_t)blockIdx.x*CB + i]=hD[i];
        histS[(size_t)blockIdx.x*CB + i]=hS[i];
    }
}

// scan along chunks for each bucket; strided access into L2/L3-resident array
__global__ __launch_bounds__(512) void k_colscan(unsigned* __restrict__ histD, unsigned* __restrict__ histS,
                          unsigned* __restrict__ ctD, unsigned* __restrict__ ctS){
    unsigned* hist = blockIdx.y ? histS : histD;
    unsigned* ct   = blockIdx.y ? ctS   : ctD;
    int b = blockIdx.x;
    __shared__ unsigned sh[512];
    unsigned v = hist[(size_t)threadIdx.x*CB + b];
    sh[threadIdx.x] = v;
    __syncthreads();
    for(int off=1; off<512; off<<=1){
        unsigned t = (threadIdx.x>=off)? sh[threadIdx.x-off] : 0u;
        __syncthreads();
        sh[threadIdx.x] += t;
        __syncthreads();
    }
    hist[(size_t)threadIdx.x*CB + b] = sh[threadIdx.x] - v;
    if(threadIdx.x==511) ct[b] = sh[511];
}

__global__ __launch_bounds__(1024) void k_bstart(const unsigned* __restrict__ ctD, const unsigned* __restrict__ ctS,
                         unsigned* __restrict__ bsD, unsigned* __restrict__ bsS){
    __shared__ unsigned sh[1024];
    unsigned v = (threadIdx.x<CB)? ctD[threadIdx.x] : 0u;
    sh[threadIdx.x]=v; __syncthreads();
    for(int off=1; off<1024; off<<=1){ unsigned t=(threadIdx.x>=off)?sh[threadIdx.x-off]:0u; __syncthreads(); sh[threadIdx.x]+=t; __syncthreads(); }
    if(threadIdx.x<CB) bsD[threadIdx.x]=sh[threadIdx.x]-v;
    if(threadIdx.x==CB-1) bsD[CB]=sh[threadIdx.x];
    __syncthreads();
    unsigned v2 = (threadIdx.x<CB)? ctS[threadIdx.x] : 0u;
    sh[threadIdx.x]=v2; __syncthreads();
    for(int off=1; off<1024; off<<=1){ unsigned t=(threadIdx.x>=off)?sh[threadIdx.x-off]:0u; __syncthreads(); sh[threadIdx.x]+=t; __syncthreads(); }
    if(threadIdx.x<CB) bsS[threadIdx.x]=sh[threadIdx.x]-v2;
    if(threadIdx.x==CB-1) bsS[CB]=sh[threadIdx.x];
}

// ==== scatter with LDS reorder: coalesced run writes =====================
__global__ __launch_bounds__(256) void k_scatter(const int* __restrict__ src, const int* __restrict__ dst,
                          const unsigned* __restrict__ histD, const unsigned* __restrict__ histS,
                          const unsigned* __restrict__ bsD, const unsigned* __restrict__ bsS,
                          unsigned* __restrict__ part, unsigned char* __restrict__ spart){
    __shared__ unsigned curD[CB], curS[CB];
    __shared__ unsigned lhD[CB], lhS[CB];
    __shared__ unsigned startD[CB], startS[CB];
    __shared__ unsigned tmp[256];
    __shared__ unsigned partl[CH];
    __shared__ unsigned short keyD[CH];
    __shared__ unsigned short keyS[CH];
    __shared__ unsigned char sl[CH];
    for(int i=threadIdx.x;i<CB;i+=256){
        curD[i]=bsD[i]+histD[(size_t)blockIdx.x*CB+i];   // contiguous reads
        curS[i]=bsS[i]+histS[(size_t)blockIdx.x*CB+i];
        lhD[i]=0; lhS[i]=0;
    }
    __syncthreads();
    int lo=blockIdx.x*CH, hi=min(lo+CH,NEDGE);
    int n = hi-lo;
    for(int e=lo+threadIdx.x;e<hi;e+=256){
        atomicAdd(&lhD[dst[e]>>8],1u);
        atomicAdd(&lhS[src[e]>>8],1u);
    }
    __syncthreads();
    scanCB(lhD, tmp);
    scanCB(lhS, tmp);
    for(int i=threadIdx.x;i<CB;i+=256){ startD[i]=lhD[i]; startS[i]=lhS[i]; }
    __syncthreads();
    for(int e=lo+threadIdx.x;e<hi;e+=256){
        int s=src[e], d=dst[e];
        unsigned bd=(unsigned)(d>>8);
        unsigned slot=atomicAdd(&lhD[bd],1u);
        partl[slot]=((unsigned)(d&255)<<18)|(unsigned)s;
        keyD[slot]=(unsigned short)bd;
        unsigned bs=(unsigned)(s>>8);
        unsigned sslot=atomicAdd(&lhS[bs],1u);
        sl[sslot]=(unsigned char)(s&255);
        keyS[sslot]=(unsigned short)bs;
    }
    __syncthreads();
    for(int k=threadIdx.x;k<n;k+=256){
        unsigned b=keyD[k];
        part[curD[b] + (unsigned)k - startD[b]] = partl[k];
    }
    for(int k=threadIdx.x;k<n;k+=256){
        unsigned b=keyS[k];
        spart[curS[b] + (unsigned)k - startS[b]] = sl[k];
    }
}

__global__ __launch_bounds__(256) void k_degO(const unsigned char* __restrict__ spart, const unsigned* __restrict__ bsS,
                       float* __restrict__ rsqO){
    __shared__ unsigned cnt[256];
    cnt[threadIdx.x]=0;
    __syncthreads();
    unsigned lo=bsS[blockIdx.x], hi=bsS[blockIdx.x+1];
    for(unsigned e=lo+threadIdx.x;e<hi;e+=256) atomicAdd(&cnt[spart[e]],1u);
    __syncthreads();
    int node=(blockIdx.x<<8)+(int)threadIdx.x;
    if(node<NNODE) rsqO[node]=rsqrtf(fmaxf((float)cnt[threadIdx.x],1.f));
}

// ==== csr: full-bucket LDS reorder + degree histogram ====================
__global__ __launch_bounds__(256) void k_csr(const unsigned* __restrict__ part, const unsigned* __restrict__ bsD,
                      const float* __restrict__ rsqO,
                      unsigned* __restrict__ rs, unsigned* __restrict__ degI,
                      unsigned* __restrict__ ec, unsigned* __restrict__ dhist){
    __shared__ unsigned cnt[256], cur[256], sh[256], ldh[DB];
    __shared__ float rsq[256];
    __shared__ unsigned partl[CAP];
    cnt[threadIdx.x]=0;
    if(threadIdx.x<DB) ldh[threadIdx.x]=0;
    __syncthreads();
    unsigned lo=bsD[blockIdx.x], hi=bsD[blockIdx.x+1];
    unsigned n = hi-lo;
    for(unsigned e=lo+threadIdx.x;e<hi;e+=256) atomicAdd(&cnt[part[e]>>18],1u);
    __syncthreads();
    unsigned c=cnt[threadIdx.x];
    sh[threadIdx.x]=c; __syncthreads();
    for(int o=1;o<256;o<<=1){ unsigned t=(threadIdx.x>=o)?sh[threadIdx.x-o]:0u; __syncthreads(); sh[threadIdx.x]+=t; __syncthreads(); }
    unsigned ex = sh[threadIdx.x]-c;
    rsq[threadIdx.x]=rsqrtf(fmaxf((float)c,1.f));
    cur[threadIdx.x]=ex;
    int node=(blockIdx.x<<8)+(int)threadIdx.x;
    if(node<NNODE){
        degI[node]=c; rs[node]=lo+ex;
        atomicAdd(&ldh[min(c,(unsigned)(DB-1))],1u);
    }
    __syncthreads();
    if(threadIdx.x<DB && ldh[threadIdx.x]) atomicAdd(&dhist[threadIdx.x], ldh[threadIdx.x]);
    if(n <= CAP){
        for(unsigned e=lo+threadIdx.x;e<hi;e+=256){
            unsigned p=part[e];
            unsigned slot=atomicAdd(&cur[p>>18],1u);
            partl[slot]=p;
        }
        __syncthreads();
        for(unsigned k=threadIdx.x;k<n;k+=256){
            unsigned p=partl[k];
            unsigned fb=p>>18, s=p&0x3FFFFu;
            float w=rsq[fb]*rsqO[s];
            unsigned w14=(unsigned)(w*16383.f + 0.5f);
            ec[lo+k]=(w14<<18)|s;
        }
    } else {
        for(unsigned e=lo+threadIdx.x;e<hi;e+=256){
            unsigned p=part[e];
            unsigned fb=p>>18, s=p&0x3FFFFu;
            unsigned pos=lo+atomicAdd(&cur[fb],1u);
            float w=rsq[fb]*rsqO[s];
            unsigned w14=(unsigned)(w*16383.f + 0.5f);
            ec[pos]=(w14<<18)|s;
        }
    }
}

// ==== degree-sorted node order (counting sort by degI) ===================
__global__ __launch_bounds__(256) void k_dorder(const unsigned* __restrict__ degI,
                        const unsigned* __restrict__ dhist, unsigned* __restrict__ dcur,
                        unsigned* __restrict__ ord){
    __shared__ unsigned dbase[DB], lh[DB], claim[DB];
    if(threadIdx.x==0){ unsigned run=0; for(int i=0;i<DB;i++){ dbase[i]=run; run+=dhist[i]; } }
    if(threadIdx.x<DB) lh[threadIdx.x]=0;
    __syncthreads();
    int node = blockIdx.x*256 + threadIdx.x;
    unsigned myb=0, myrank=0; bool valid = node<NNODE;
    if(valid){ myb = min(degI[node],(unsigned)(DB-1)); myrank = atomicAdd(&lh[myb],1u); }
    __syncthreads();
    if(threadIdx.x<DB && lh[threadIdx.x]) claim[threadIdx.x] = atomicAdd(&dcur[threadIdx.x], lh[threadIdx.x]);
    __syncthreads();
    if(valid) ord[dbase[myb] + claim[myb] + myrank] = (unsigned)node;
}

// ==== SpMM: one wave per 4 degree-matched rows ===========================
__device__ __forceinline__ void drain_row(const unsigned short* __restrict__ hin,
                                          const unsigned* __restrict__ ec,
                                          unsigned s, unsigned c, unsigned &i, int lane,
                                          float &ax, float &ay){
    for(; i+4<=c; i+=4){
        unsigned e0=ec[s+i], e1=ec[s+i+1], e2=ec[s+i+2], e3=ec[s+i+3];
        unsigned short u0=hin[(size_t)(e0&0x3FFFFu)*64+lane];
        unsigned short u1=hin[(size_t)(e1&0x3FFFFu)*64+lane];
        unsigned short u2=hin[(size_t)(e2&0x3FFFFu)*64+lane];
        unsigned short u3=hin[(size_t)(e3&0x3FFFFu)*64+lane];
        float w0=(float)(e0>>18)*(1.f/16383.f), w1=(float)(e1>>18)*(1.f/16383.f);
        float w2=(float)(e2>>18)*(1.f/16383.f), w3=(float)(e3>>18)*(1.f/16383.f);
        v2f v;
        v=fp8x2_to_f32(u0); ax+=w0*v.x; ay+=w0*v.y;
        v=fp8x2_to_f32(u1); ax+=w1*v.x; ay+=w1*v.y;
        v=fp8x2_to_f32(u2); ax+=w2*v.x; ay+=w2*v.y;
        v=fp8x2_to_f32(u3); ax+=w3*v.x; ay+=w3*v.y;
    }
    for(; i<c; ++i){
        unsigned e0=ec[s+i];
        unsigned short u0=hin[(size_t)(e0&0x3FFFFu)*64+lane];
        float w0=(float)(e0>>18)*(1.f/16383.f);
        v2f v=fp8x2_to_f32(u0); ax+=w0*v.x; ay+=w0*v.y;
    }
}

__global__ __launch_bounds__(256) void k_spmm_c(const unsigned short* __restrict__ hin, unsigned short* __restrict__ hout,
                                                const unsigned* __restrict__ rs, const unsigned* __restrict__ degI,
                                                const unsigned* __restrict__ ec, const unsigned* __restrict__ ord){
    int wv = (blockIdx.x*256 + threadIdx.x) >> 6;
    int lane = threadIdx.x & 63;
    if(4*wv >= NNODE) return;
    unsigned r0=rfl(ord[4*wv  ]), r1=rfl(ord[4*wv+1]);
    unsigned r2=rfl(ord[4*wv+2]), r3=rfl(ord[4*wv+3]);
    unsigned s0=rfl(rs[r0]), c0=rfl(degI[r0]);
    unsigned s1=rfl(rs[r1]), c1=rfl(degI[r1]);
    unsigned s2=rfl(rs[r2]), c2=rfl(degI[r2]);
    unsigned s3=rfl(rs[r3]), c3=rfl(degI[r3]);
    float ax0=0,ay0=0, ax1=0,ay1=0, ax2=0,ay2=0, ax3=0,ay3=0;
    unsigned i0=0,i1=0,i2=0,i3=0;
    while(i0+4<=c0 && i1+4<=c1 && i2+4<=c2 && i3+4<=c3){
        unsigned e00=ec[s0+i0], e01=ec[s0+i0+1], e02=ec[s0+i0+2], e03=ec[s0+i0+3];
        unsigned e10=ec[s1+i1], e11=ec[s1+i1+1], e12=ec[s1+i1+2], e13=ec[s1+i1+3];
        unsigned e20=ec[s2+i2], e21=ec[s2+i2+1], e22=ec[s2+i2+2], e23=ec[s2+i2+3];
        unsigned e30=ec[s3+i3], e31=ec[s3+i3+1], e32=ec[s3+i3+2], e33=ec[s3+i3+3];
        unsigned short u00=hin[(size_t)(e00&0x3FFFFu)*64+lane];
        unsigned short u01=hin[(size_t)(e01&0x3FFFFu)*64+lane];
        unsigned short u02=hin[(size_t)(e02&0x3FFFFu)*64+lane];
        unsigned short u03=hin[(size_t)(e03&0x3FFFFu)*64+lane];
        unsigned short u10=hin[(size_t)(e10&0x3FFFFu)*64+lane];
        unsigned short u11=hin[(size_t)(e11&0x3FFFFu)*64+lane];
        unsigned short u12=hin[(size_t)(e12&0x3FFFFu)*64+lane];
        unsigned short u13=hin[(size_t)(e13&0x3FFFFu)*64+lane];
        unsigned short u20=hin[(size_t)(e20&0x3FFFFu)*64+lane];
        unsigned short u21=hin[(size_t)(e21&0x3FFFFu)*64+lane];
        unsigned short u22=hin[(size_t)(e22&0x3FFFFu)*64+lane];
        unsigned short u23=hin[(size_t)(e23&0x3FFFFu)*64+lane];
        unsigned short u30=hin[(size_t)(e30&0x3FFFFu)*64+lane];
        unsigned short u31=hin[(size_t)(e31&0x3FFFFu)*64+lane];
        unsigned short u32v=hin[(size_t)(e32&0x3FFFFu)*64+lane];
        unsigned short u33=hin[(size_t)(e33&0x3FFFFu)*64+lane];
        v2f v; float w;
        v=fp8x2_to_f32(u00); w=(float)(e00>>18)*(1.f/16383.f); ax0+=w*v.x; ay0+=w*v.y;
        v=fp8x2_to_f32(u01); w=(float)(e01>>18)*(1.f/16383.f); ax0+=w*v.x; ay0+=w*v.y;
        v=fp8x2_to_f32(u02); w=(float)(e02>>18)*(1.f/16383.f); ax0+=w*v.x; ay0+=w*v.y;
        v=fp8x2_to_f32(u03); w=(float)(e03>>18)*(1.f/16383.f); ax0+=w*v.x; ay0+=w*v.y;
        v=fp8x2_to_f32(u10); w=(float)(e10>>18)*(1.f/16383.f); ax1+=w*v.x; ay1+=w*v.y;
        v=fp8x2_to_f32(u11); w=(float)(e11>>18)*(1.f/16383.f); ax1+=w*v.x; ay1+=w*v.y;
        v=fp8x2_to_f32(u12); w=(float)(e12>>18)*(1.f/16383.f); ax1+=w*v.x; ay1+=w*v.y;
        v=fp8x2_to_f32(u13); w=(float)(e13>>18)*(1.f/16383.f); ax1+=w*v.x; ay1+=w*v.y;
        v=fp8x2_to_f32(u20); w=(float)(e20>>18)*(1.f/16383.f); ax2+=w*v.x; ay2+=w*v.y;
        v=fp8x2_to_f32(u21); w=(float)(e21>>18)*(1.f/16383.f); ax2+=w*v.x; ay2+=w*v.y;
        v=fp8x2_to_f32(u22); w=(float)(e22>>18)*(1.f/16383.f); ax2+=w*v.x; ay2+=w*v.y;
        v=fp8x2_to_f32(u23); w=(float)(e23>>18)*(1.f/16383.f); ax2+=w*v.x; ay2+=w*v.y;
        v=fp8x2_to_f32(u30); w=(float)(e30>>18)*(1.f/16383.f); ax3+=w*v.x; ay3+=w*v.y;
        v=fp8x2_to_f32(u31); w=(float)(e31>>18)*(1.f/16383.f); ax3+=w*v.x; ay3+=w*v.y;
        v=fp8x2_to_f32(u32v); w=(float)(e32>>18)*(1.f/16383.f); ax3+=w*v.x; ay3+=w*v.y;
        v=fp8x2_to_f32(u33); w=(float)(e33>>18)*(1.f/16383.f); ax3+=w*v.x; ay3+=w*v.y;
        i0+=4; i1+=4; i2+=4; i3+=4;
    }
    drain_row(hin, ec, s0, c0, i0, lane, ax0, ay0);
    drain_row(hin, ec, s1, c1, i1, lane, ax1, ay1);
    drain_row(hin, ec, s2, c2, i2, lane, ax2, ay2);
    drain_row(hin, ec, s3, c3, i3, lane, ax3, ay3);
    hout[(size_t)r0*64+lane] = f32_to_fp8x2(ax0, ay0);
    hout[(size_t)r1*64+lane] = f32_to_fp8x2(ax1, ay1);
    hout[(size_t)r2*64+lane] = f32_to_fp8x2(ax2, ay2);
    hout[(size_t)r3*64+lane] = f32_to_fp8x2(ax3, ay3);
}

// layer-3 SpMM at target-pair slots, fp32 float2 output rows
__global__ __launch_bounds__(256) void k_spmm_t(const unsigned short* __restrict__ hin, float2* __restrict__ h3,
                                                const unsigned* __restrict__ rs, const unsigned* __restrict__ degI,
                                                const unsigned* __restrict__ ec,
                                                const int* __restrict__ user, const int* __restrict__ itp,
                                                const int* __restrict__ itn){
    int wv = (blockIdx.x*256 + threadIdx.x) >> 6;
    int lane = threadIdx.x & 63;
    int t0 = 2*wv, t1 = 2*wv+1;
    if(t0 >= NTGT) return;
    int sec0 = t0>>13, b0 = t0&(BSZ-1);
    int sec1 = t1>>13, b1 = t1&(BSZ-1);
    int n0 = (sec0==0) ? user[b0] : ((sec0==1) ? itp[b0]+N_USER : itn[b0]+N_USER);
    int n1 = (sec1==0) ? user[b1] : ((sec1==1) ? itp[b1]+N_USER : itn[b1]+N_USER);
    n0 = __builtin_amdgcn_readfirstlane(n0);
    n1 = __builtin_amdgcn_readfirstlane(n1);
    unsigned s0 = rfl(rs[n0]), c0 = rfl(degI[n0]);
    unsigned s1 = rfl(rs[n1]), c1 = rfl(degI[n1]);
    float ax0=0.f, ay0=0.f, ax1=0.f, ay1=0.f;
    unsigned i0=0, i1=0;
    while(i0+4<=c0 && i1+4<=c1){
        unsigned e0=ec[s0+i0], e1=ec[s0+i0+1], e2=ec[s0+i0+2], e3=ec[s0+i0+3];
        unsigned e4=ec[s1+i1], e5=ec[s1+i1+1], e6=ec[s1+i1+2], e7=ec[s1+i1+3];
        unsigned short u0=hin[(size_t)(e0&0x3FFFFu)*64+lane];
        unsigned short u1=hin[(size_t)(e1&0x3FFFFu)*64+lane];
        unsigned short u2=hin[(size_t)(e2&0x3FFFFu)*64+lane];
        unsigned short u3=hin[(size_t)(e3&0x3FFFFu)*64+lane];
        unsigned short u4=hin[(size_t)(e4&0x3FFFFu)*64+lane];
        unsigned short u5=hin[(size_t)(e5&0x3FFFFu)*64+lane];
        unsigned short u6=hin[(size_t)(e6&0x3FFFFu)*64+lane];
        unsigned short u7=hin[(size_t)(e7&0x3FFFFu)*64+lane];
        float w0=(float)(e0>>18)*(1.f/16383.f), w1=(float)(e1>>18)*(1.f/16383.f);
        float w2=(float)(e2>>18)*(1.f/16383.f), w3=(float)(e3>>18)*(1.f/16383.f);
        float w4=(float)(e4>>18)*(1.f/16383.f), w5=(float)(e5>>18)*(1.f/16383.f);
        float w6=(float)(e6>>18)*(1.f/16383.f), w7=(float)(e7>>18)*(1.f/16383.f);
        v2f v;
        v=fp8x2_to_f32(u0); ax0+=w0*v.x; ay0+=w0*v.y;
        v=fp8x2_to_f32(u1); ax0+=w1*v.x; ay0+=w1*v.y;
        v=fp8x2_to_f32(u2); ax0+=w2*v.x; ay0+=w2*v.y;
        v=fp8x2_to_f32(u3); ax0+=w3*v.x; ay0+=w3*v.y;
        v=fp8x2_to_f32(u4); ax1+=w4*v.x; ay1+=w4*v.y;
        v=fp8x2_to_f32(u5); ax1+=w5*v.x; ay1+=w5*v.y;
        v=fp8x2_to_f32(u6); ax1+=w6*v.x; ay1+=w6*v.y;
        v=fp8x2_to_f32(u7); ax1+=w7*v.x; ay1+=w7*v.y;
        i0+=4; i1+=4;
    }
    drain_row(hin, ec, s0, c0, i0, lane, ax0, ay0);
    drain_row(hin, ec, s1, c1, i1, lane, ax1, ay1);
    h3[(size_t)t0*64+lane] = make_float2(ax0, ay0);
    h3[(size_t)t1*64+lane] = make_float2(ax1, ay1);
}

// ==== fused gather + score + loss: one wave per sample ===================
__global__ __launch_bounds__(256) void k_scoreloss(const float2* __restrict__ ei, const float2* __restrict__ ep,
                        const unsigned short* __restrict__ h1C, const unsigned short* __restrict__ h2C,
                        const float2* __restrict__ h3,
                        const float* __restrict__ q, const float* __restrict__ bq,
                        const int* __restrict__ user, const int* __restrict__ item_p, const int* __restrict__ item_n,
                        const void* __restrict__ mask, const unsigned* __restrict__ mflag,
                        float4* __restrict__ partial){
    int t = blockIdx.x*256 + threadIdx.x;
    int b = t >> 6, l = t & 63;
    int wv = threadIdx.x >> 6;
    __shared__ float4 wsum[4];
    int nu = user[b];
    int np = item_p[b] + N_USER;
    int nn = item_n[b] + N_USER;

    float2 e0u, e0p, e0n;
    if(l < 32){
        e0u = ei[(size_t)nu*32 + l]; e0p = ei[(size_t)np*32 + l]; e0n = ei[(size_t)nn*32 + l];
    } else {
        e0u = ep[(size_t)nu*32 + (l-32)]; e0p = ep[(size_t)np*32 + (l-32)]; e0n = ep[(size_t)nn*32 + (l-32)];
    }
    v2f h1u = fp8x2_to_f32(h1C[(size_t)nu*64 + l]);
    v2f h1p = fp8x2_to_f32(h1C[(size_t)np*64 + l]);
    v2f h1n = fp8x2_to_f32(h1C[(size_t)nn*64 + l]);
    v2f h2u = fp8x2_to_f32(h2C[(size_t)nu*64 + l]);
    v2f h2p = fp8x2_to_f32(h2C[(size_t)np*64 + l]);
    v2f h2n = fp8x2_to_f32(h2C[(size_t)nn*64 + l]);
    float2 h3u = h3[(size_t)b*64 + l];
    float2 h3p = h3[(size_t)(BSZ   + b)*64 + l];
    float2 h3n = h3[(size_t)(2*BSZ + b)*64 + l];

    float fux = e0u.x + h1u.x + h2u.x + h3u.x, fuy = e0u.y + h1u.y + h2u.y + h3u.y;
    float fpx = e0p.x + h1p.x + h2p.x + h3p.x, fpy = e0p.y + h1p.y + h2p.y + h3p.y;
    float fnx = e0n.x + h1n.x + h2n.x + h3n.x, fny = e0n.y + h1n.y + h2n.y + h3n.y;

    float dp = fux*fpx + fuy*fpy;
    float dn = fux*fnx + fuy*fny;
    for(int off=16; off; off>>=1){ dp += __shfl_down(dp,off,32); dn += __shfl_down(dn,off,32); }
    float pi  = __shfl(dp, 0, 64) * (1.f/16.f);
    float ni  = __shfl(dn, 0, 64) * (1.f/16.f);
    float pp  = __shfl(dp, 32, 64) * (1.f/16.f);
    float npp = __shfl(dn, 32, 64) * (1.f/16.f);
    if(l == 0){
        bool bytes = (*mflag)!=0;
        float mf = bytes ? (((const unsigned char*)mask)[b]?1.f:0.f)
                         : (((const int*)mask)[b]?1.f:0.f);
        float nmf = 1.f-mf;
        float a0 = mf  * logsigf(pi-ni);
        float a1 = mf  * logsigf(npp-pp);
        float a2 = nmf * logsigf(pp-npp);
        int ip=item_p[b], in_=item_n[b];
        float popp = softplusf(q[ip]) + softplusf(bq[ip]);
        float popn = softplusf(q[in_]) + softplusf(bq[in_]);
        float a3 = logsigf(tanhf(popp)*(pi+pp) - tanhf(popn)*(ni+npp));
        wsum[wv] = make_float4(a0,a1,a2,a3);
    }
    __syncthreads();
    if(threadIdx.x == 0){
        float4 s0=wsum[0], s1=wsum[1], s2=wsum[2], s3=wsum[3];
        partial[blockIdx.x] = make_float4(s0.x+s1.x+s2.x+s3.x, s0.y+s1.y+s2.y+s3.y,
                                          s0.z+s1.z+s2.z+s3.z, s0.w+s1.w+s2.w+s3.w);
    }
}

__global__ __launch_bounds__(256) void k_lossfin(const float4* __restrict__ partial, float* __restrict__ out){
    __shared__ float4 sh[256];
    float4 s = make_float4(0,0,0,0);
    for(int i=threadIdx.x; i<LBLK; i+=256){
        float4 v = partial[i];
        s.x+=v.x; s.y+=v.y; s.z+=v.z; s.w+=v.w;
    }
    sh[threadIdx.x]=s;
    __syncthreads();
    for(int off=128; off; off>>=1){
        if(threadIdx.x < off){
            float4 a=sh[threadIdx.x], b2=sh[threadIdx.x+off];
            sh[threadIdx.x]=make_float4(a.x+b2.x,a.y+b2.y,a.z+b2.z,a.w+b2.w);
        }
        __syncthreads();
    }
    if(threadIdx.x==0){
        const float invB = 1.f/(float)BSZ;
        float4 t = sh[0];
        float loss_int  = -t.x*invB;
        float loss_pop  = -t.y*invB + t.z*invB;
        float loss_tide = -t.w*invB;
        out[0] = 0.1f*loss_int + 0.1f*loss_pop + 0.2f*loss_tide;
    }
}

extern "C" void kernel_launch(void* const* d_in, const int* in_sizes, int n_in,
                              void* d_out, int out_size, void* d_ws, size_t ws_size,
                              hipStream_t stream){
    const float* emb_int = (const float*)d_in[0];
    const float* emb_pop = (const float*)d_in[1];
    const float* q    = (const float*)d_in[2];
    const float* bq   = (const float*)d_in[3];
    const int* user   = (const int*)d_in[4];
    const int* item_p = (const int*)d_in[5];
    const int* item_n = (const int*)d_in[6];
    const void* mask  = d_in[7];
    const int* esrc   = (const int*)d_in[8];
    const int* edst   = (const int*)d_in[9];

    char* ws = (char*)d_ws;
    size_t o = 0;
    auto take = [&](size_t bytes)->char*{ char* p = ws + o; o = (o + bytes + 255) & ~(size_t)255; return p; };
    unsigned* histD = (unsigned*)take((size_t)NB*CB*4);
    unsigned* histS = (unsigned*)take((size_t)NB*CB*4);
    unsigned* ctD   = (unsigned*)take((size_t)CB*4);
    unsigned* ctS   = (unsigned*)take((size_t)CB*4);
    unsigned* bsD   = (unsigned*)take((size_t)(CB+1)*4);
    unsigned* bsS   = (unsigned*)take((size_t)(CB+1)*4);
    unsigned* part  = (unsigned*)take((size_t)NEDGE*4);
    unsigned char* spart = (unsigned char*)take((size_t)NEDGE);
    float*    rsqO  = (float*)take((size_t)NNODE*4);
    unsigned* degI  = (unsigned*)take((size_t)NNODE*4);
    unsigned* rs    = (unsigned*)take((size_t)NNODE*4);
    unsigned* ec    = (unsigned*)take((size_t)NEDGE*4);
    unsigned short* hE  = (unsigned short*)take((size_t)NNODE*64*2);
    unsigned short* h1C = (unsigned short*)take((size_t)NNODE*64*2);
    unsigned short* h2C = (unsigned short*)take((size_t)NNODE*64*2);
    float2*   h3    = (float2*)take((size_t)NTGT*64*8);
    float4*   partial = (float4*)take((size_t)LBLK*16);
    unsigned* mflag = (unsigned*)take(256);
    unsigned* dhist = (unsigned*)take((size_t)DB*4);
    unsigned* dcur  = (unsigned*)take((size_t)DB*4);
    unsigned* ord   = (unsigned*)take((size_t)NNODE*4);
    (void)ws_size; (void)in_sizes; (void)n_in; (void)out_size;

    // fused: coarse hist ([chunk][bin]) + fp8 prep + mask detect + dhist zero
    k_hist<<<NB + PREPB + 1,256,0,stream>>>(esrc, edst, histD, histS,
                                            (const float2*)emb_int, (const float2*)emb_pop,
                                            (unsigned*)hE, (const unsigned char*)mask, mflag,
                                            dhist, dcur);
    k_colscan<<<dim3(CB,2),512,0,stream>>>(histD, histS, ctD, ctS);
    k_bstart<<<1,1024,0,stream>>>(ctD, ctS, bsD, bsS);
    k_scatter<<<NB,256,0,stream>>>(esrc, edst, histD, histS, bsD, bsS, part, spart);
    k_degO<<<CB,256,0,stream>>>(spart, bsS, rsqO);
    k_csr<<<CB,256,0,stream>>>(part, bsD, rsqO, rs, degI, ec, dhist);
    k_dorder<<<CB,256,0,stream>>>(degI, dhist, dcur, ord);

    const int spB = ((NNODE/4)*64 + 255)/256;     // one wave per 4 rows
    k_spmm_c<<<spB,256,0,stream>>>(hE,  h1C, rs, degI, ec, ord);  // layer 1
    k_spmm_c<<<spB,256,0,stream>>>(h1C, h2C, rs, degI, ec, ord);  // layer 2
    k_spmm_t<<<((NTGT/2)*64 + 255)/256,256,0,stream>>>(h2C, h3, rs, degI, ec,
                                                 user, item_p, item_n);                  // layer 3
    k_scoreloss<<<LBLK,256,0,stream>>>((const float2*)emb_int, (const float2*)emb_pop,
                                       h1C, h2C, h3, q, bq, user, item_p, item_n,
                                       mask, mflag, partial);
    k_lossfin<<<1,256,0,stream>>>(partial, (float*)d_out);
}

// Round 10
// 348.267 us; speedup vs baseline: 1.0602x; 1.0602x over previous
//
#include <hip/hip_runtime.h>
#include <hip/hip_bf16.h>
#include <math.h>

#define N_USER 100000
#define N_ITEM 50000
#define NNODE  150000   // N_USER + N_ITEM
#define DIM    64
#define NEDGE  2000000
#define BSZ    8192
#define NTGT   (3*BSZ)
#define CB     586      // ceil(NNODE/256) coarse buckets
#define NB     512      // edge chunks
#define CH     ((NEDGE + NB - 1)/NB)   // 3907
#define LBLK   2048
#define PREPB  (NNODE*32/256)   // 18750 prep blocks (u32 outputs)
#define CAP    5120     // k_csr per-bucket LDS capacity

typedef float v2f __attribute__((ext_vector_type(2)));

__device__ __forceinline__ float logsigf(float x){
    return fminf(x, 0.f) - log1pf(expf(-fabsf(x)));
}
__device__ __forceinline__ float softplusf(float x){
    return fmaxf(x, 0.f) + log1pf(expf(-fabsf(x)));
}
__device__ __forceinline__ v2f fp8x2_to_f32(unsigned short u){
    return __builtin_amdgcn_cvt_pk_f32_fp8((int)u, false);
}
__device__ __forceinline__ unsigned short f32_to_fp8x2(float a, float b){
    return (unsigned short)__builtin_amdgcn_cvt_pk_fp8_f32(a, b, 0, false);
}
__device__ __forceinline__ unsigned rfl(unsigned v){
    return (unsigned)__builtin_amdgcn_readfirstlane((int)v);
}

// exclusive scan of arr[CB] in LDS with 256 threads (each owns 3 slots)
__device__ __forceinline__ void scanCB(unsigned* arr, unsigned* tmp){
    int t = threadIdx.x;
    int base = 3*t;
    unsigned a0=0,a1=0,a2=0;
    if(base   < CB) a0 = arr[base];
    if(base+1 < CB) a1 = arr[base+1];
    if(base+2 < CB) a2 = arr[base+2];
    unsigned s = a0+a1+a2;
    tmp[t]=s; __syncthreads();
    for(int off=1; off<256; off<<=1){
        unsigned v = (t>=off)? tmp[t-off] : 0u;
        __syncthreads();
        tmp[t] += v;
        __syncthreads();
    }
    unsigned excl = tmp[t]-s;
    if(base   < CB) arr[base]   = excl;
    if(base+1 < CB) arr[base+1] = excl+a0;
    if(base+2 < CB) arr[base+2] = excl+a0+a1;
    __syncthreads();
}

// ==== fused: coarse histograms ([chunk][bin] layout) + fp8 prep + mask ===
__global__ __launch_bounds__(256) void k_hist(const int* __restrict__ src, const int* __restrict__ dst,
                       unsigned* __restrict__ histD, unsigned* __restrict__ histS,
                       const float2* __restrict__ ei, const float2* __restrict__ ep,
                       unsigned* __restrict__ hC32,
                       const unsigned char* __restrict__ mask8, unsigned* __restrict__ mflag){
    if(blockIdx.x >= NB){
        if(blockIdx.x == NB + PREPB){
            __shared__ int any;
            if(threadIdx.x==0) any=0;
            __syncthreads();
            for(int i=threadIdx.x;i<BSZ;i+=256){ if((i&3) && mask8[i]) any=1; }
            __syncthreads();
            if(threadIdx.x==0) *mflag = (any!=0) ? 1u : 0u;
            return;
        }
        int idx = (blockIdx.x - NB)*256 + threadIdx.x;
        int n = idx>>5, c = idx&31;
        float2 va, vb;
        if(c<16){ va = ei[(size_t)n*32 + 2*c]; vb = ei[(size_t)n*32 + 2*c+1]; }
        else    { va = ep[(size_t)n*32 + 2*c-32]; vb = ep[(size_t)n*32 + 2*c-31]; }
        int d = __builtin_amdgcn_cvt_pk_fp8_f32(va.x, va.y, 0, false);
        d = __builtin_amdgcn_cvt_pk_fp8_f32(vb.x, vb.y, d, true);
        hC32[(size_t)n*32 + c] = (unsigned)d;
        return;
    }
    __shared__ unsigned hD[CB], hS[CB];
    for(int i=threadIdx.x;i<CB;i+=256){ hD[i]=0; hS[i]=0; }
    __syncthreads();
    int lo = blockIdx.x*CH, hi = min(lo+CH, NEDGE);
    for(int e=lo+threadIdx.x; e<hi; e+=256){
        atomicAdd(&hS[src[e]>>8],1u);
        atomicAdd(&hD[dst[e]>>8],1u);
    }
    __syncthreads();
    for(int i=threadIdx.x;i<CB;i+=256){          // contiguous full-line writes
        histD[(size_t)blockIdx.x*CB + i]=hD[i];
        histS[(size_t)blockIdx.x*CB + i]=hS[i];
    }
}

// scan along chunks for each bucket; strided access into L2/L3-resident array
__global__ __launch_bounds__(512) void k_colscan(unsigned* __restrict__ histD, unsigned* __restrict__ histS,
                          unsigned* __restrict__ ctD, unsigned* __restrict__ ctS){
    unsigned* hist = blockIdx.y ? histS : histD;
    unsigned* ct   = blockIdx.y ? ctS   : ctD;
    int b = blockIdx.x;
    __shared__ unsigned sh[512];
    unsigned v = hist[(size_t)threadIdx.x*CB + b];
    sh[threadIdx.x] = v;
    __syncthreads();
    for(int off=1; off<512; off<<=1){
        unsigned t = (threadIdx.x>=off)? sh[threadIdx.x-off] : 0u;
        __syncthreads();
        sh[threadIdx.x] += t;
        __syncthreads();
    }
    hist[(size_t)threadIdx.x*CB + b] = sh[threadIdx.x] - v;
    if(threadIdx.x==511) ct[b] = sh[511];
}

__global__ __launch_bounds__(1024) void k_bstart(const unsigned* __restrict__ ctD, const unsigned* __restrict__ ctS,
                         unsigned* __restrict__ bsD, unsigned* __restrict__ bsS){
    __shared__ unsigned sh[1024];
    unsigned v = (threadIdx.x<CB)? ctD[threadIdx.x] : 0u;
    sh[threadIdx.x]=v; __syncthreads();
    for(int off=1; off<1024; off<<=1){ unsigned t=(threadIdx.x>=off)?sh[threadIdx.x-off]:0u; __syncthreads(); sh[threadIdx.x]+=t; __syncthreads(); }
    if(threadIdx.x<CB) bsD[threadIdx.x]=sh[threadIdx.x]-v;
    if(threadIdx.x==CB-1) bsD[CB]=sh[threadIdx.x];
    __syncthreads();
    unsigned v2 = (threadIdx.x<CB)? ctS[threadIdx.x] : 0u;
    sh[threadIdx.x]=v2; __syncthreads();
    for(int off=1; off<1024; off<<=1){ unsigned t=(threadIdx.x>=off)?sh[threadIdx.x-off]:0u; __syncthreads(); sh[threadIdx.x]+=t; __syncthreads(); }
    if(threadIdx.x<CB) bsS[threadIdx.x]=sh[threadIdx.x]-v2;
    if(threadIdx.x==CB-1) bsS[CB]=sh[threadIdx.x];
}

// ==== scatter with LDS reorder: coalesced run writes =====================
__global__ __launch_bounds__(256) void k_scatter(const int* __restrict__ src, const int* __restrict__ dst,
                          const unsigned* __restrict__ histD, const unsigned* __restrict__ histS,
                          const unsigned* __restrict__ bsD, const unsigned* __restrict__ bsS,
                          unsigned* __restrict__ part, unsigned char* __restrict__ spart){
    __shared__ unsigned curD[CB], curS[CB];
    __shared__ unsigned lhD[CB], lhS[CB];
    __shared__ unsigned startD[CB], startS[CB];
    __shared__ unsigned tmp[256];
    __shared__ unsigned partl[CH];
    __shared__ unsigned short keyD[CH];
    __shared__ unsigned short keyS[CH];
    __shared__ unsigned char sl[CH];
    for(int i=threadIdx.x;i<CB;i+=256){
        curD[i]=bsD[i]+histD[(size_t)blockIdx.x*CB+i];
        curS[i]=bsS[i]+histS[(size_t)blockIdx.x*CB+i];
        lhD[i]=0; lhS[i]=0;
    }
    __syncthreads();
    int lo=blockIdx.x*CH, hi=min(lo+CH,NEDGE);
    int n = hi-lo;
    for(int e=lo+threadIdx.x;e<hi;e+=256){
        atomicAdd(&lhD[dst[e]>>8],1u);
        atomicAdd(&lhS[src[e]>>8],1u);
    }
    __syncthreads();
    scanCB(lhD, tmp);
    scanCB(lhS, tmp);
    for(int i=threadIdx.x;i<CB;i+=256){ startD[i]=lhD[i]; startS[i]=lhS[i]; }
    __syncthreads();
    for(int e=lo+threadIdx.x;e<hi;e+=256){
        int s=src[e], d=dst[e];
        unsigned bd=(unsigned)(d>>8);
        unsigned slot=atomicAdd(&lhD[bd],1u);
        partl[slot]=((unsigned)(d&255)<<18)|(unsigned)s;
        keyD[slot]=(unsigned short)bd;
        unsigned bs=(unsigned)(s>>8);
        unsigned sslot=atomicAdd(&lhS[bs],1u);
        sl[sslot]=(unsigned char)(s&255);
        keyS[sslot]=(unsigned short)bs;
    }
    __syncthreads();
    for(int k=threadIdx.x;k<n;k+=256){
        unsigned b=keyD[k];
        part[curD[b] + (unsigned)k - startD[b]] = partl[k];
    }
    for(int k=threadIdx.x;k<n;k+=256){
        unsigned b=keyS[k];
        spart[curS[b] + (unsigned)k - startS[b]] = sl[k];
    }
}

__global__ __launch_bounds__(256) void k_degO(const unsigned char* __restrict__ spart, const unsigned* __restrict__ bsS,
                       float* __restrict__ rsqO){
    __shared__ unsigned cnt[256];
    cnt[threadIdx.x]=0;
    __syncthreads();
    unsigned lo=bsS[blockIdx.x], hi=bsS[blockIdx.x+1];
    for(unsigned e=lo+threadIdx.x;e<hi;e+=256) atomicAdd(&cnt[spart[e]],1u);
    __syncthreads();
    int node=(blockIdx.x<<8)+(int)threadIdx.x;
    if(node<NNODE) rsqO[node]=rsqrtf(fmaxf((float)cnt[threadIdx.x],1.f));
}

// ==== csr: full-bucket LDS reorder -> linear ec writes ===================
__global__ __launch_bounds__(256) void k_csr(const unsigned* __restrict__ part, const unsigned* __restrict__ bsD,
                      const float* __restrict__ rsqO,
                      unsigned* __restrict__ rs, unsigned* __restrict__ degI,
                      unsigned* __restrict__ ec){
    __shared__ unsigned cnt[256], cur[256], sh[256];
    __shared__ float rsq[256];
    __shared__ unsigned partl[CAP];
    cnt[threadIdx.x]=0;
    __syncthreads();
    unsigned lo=bsD[blockIdx.x], hi=bsD[blockIdx.x+1];
    unsigned n = hi-lo;
    for(unsigned e=lo+threadIdx.x;e<hi;e+=256) atomicAdd(&cnt[part[e]>>18],1u);
    __syncthreads();
    unsigned c=cnt[threadIdx.x];
    sh[threadIdx.x]=c; __syncthreads();
    for(int o=1;o<256;o<<=1){ unsigned t=(threadIdx.x>=o)?sh[threadIdx.x-o]:0u; __syncthreads(); sh[threadIdx.x]+=t; __syncthreads(); }
    unsigned ex = sh[threadIdx.x]-c;
    rsq[threadIdx.x]=rsqrtf(fmaxf((float)c,1.f));
    cur[threadIdx.x]=ex;
    int node=(blockIdx.x<<8)+(int)threadIdx.x;
    if(node<NNODE){ degI[node]=c; rs[node]=lo+ex; }
    __syncthreads();
    if(n <= CAP){
        for(unsigned e=lo+threadIdx.x;e<hi;e+=256){
            unsigned p=part[e];
            unsigned slot=atomicAdd(&cur[p>>18],1u);
            partl[slot]=p;
        }
        __syncthreads();
        for(unsigned k=threadIdx.x;k<n;k+=256){
            unsigned p=partl[k];
            unsigned fb=p>>18, s=p&0x3FFFFu;
            float w=rsq[fb]*rsqO[s];
            unsigned w14=(unsigned)(w*16383.f + 0.5f);
            ec[lo+k]=(w14<<18)|s;
        }
    } else {
        for(unsigned e=lo+threadIdx.x;e<hi;e+=256){
            unsigned p=part[e];
            unsigned fb=p>>18, s=p&0x3FFFFu;
            unsigned pos=lo+atomicAdd(&cur[fb],1u);
            float w=rsq[fb]*rsqO[s];
            unsigned w14=(unsigned)(w*16383.f + 0.5f);
            ec[pos]=(w14<<18)|s;
        }
    }
}

// ==== SpMM: one wave per 4 CONSECUTIVE rows; nt edge stream ==============
__device__ __forceinline__ void drain_row(const unsigned short* __restrict__ hin,
                                          const unsigned* __restrict__ ec,
                                          unsigned s, unsigned c, unsigned &i, int lane,
                                          float &ax, float &ay){
    for(; i+4<=c; i+=4){
        unsigned e0=__builtin_nontemporal_load(&ec[s+i]);
        unsigned e1=__builtin_nontemporal_load(&ec[s+i+1]);
        unsigned e2=__builtin_nontemporal_load(&ec[s+i+2]);
        unsigned e3=__builtin_nontemporal_load(&ec[s+i+3]);
        unsigned short u0=hin[(size_t)(e0&0x3FFFFu)*64+lane];
        unsigned short u1=hin[(size_t)(e1&0x3FFFFu)*64+lane];
        unsigned short u2=hin[(size_t)(e2&0x3FFFFu)*64+lane];
        unsigned short u3=hin[(size_t)(e3&0x3FFFFu)*64+lane];
        float w0=(float)(e0>>18)*(1.f/16383.f), w1=(float)(e1>>18)*(1.f/16383.f);
        float w2=(float)(e2>>18)*(1.f/16383.f), w3=(float)(e3>>18)*(1.f/16383.f);
        v2f v;
        v=fp8x2_to_f32(u0); ax+=w0*v.x; ay+=w0*v.y;
        v=fp8x2_to_f32(u1); ax+=w1*v.x; ay+=w1*v.y;
        v=fp8x2_to_f32(u2); ax+=w2*v.x; ay+=w2*v.y;
        v=fp8x2_to_f32(u3); ax+=w3*v.x; ay+=w3*v.y;
    }
    for(; i<c; ++i){
        unsigned e0=__builtin_nontemporal_load(&ec[s+i]);
        unsigned short u0=hin[(size_t)(e0&0x3FFFFu)*64+lane];
        float w0=(float)(e0>>18)*(1.f/16383.f);
        v2f v=fp8x2_to_f32(u0); ax+=w0*v.x; ay+=w0*v.y;
    }
}

__global__ __launch_bounds__(256) void k_spmm_c(const unsigned short* __restrict__ hin, unsigned short* __restrict__ hout,
                                                const unsigned* __restrict__ rs, const unsigned* __restrict__ degI,
                                                const unsigned* __restrict__ ec){
    int wv = (blockIdx.x*256 + threadIdx.x) >> 6;
    int lane = threadIdx.x & 63;
    int r = 4*wv;                         // NNODE % 4 == 0, natural order
    if(r >= NNODE) return;
    unsigned s0=rfl(rs[r  ]), c0=rfl(degI[r  ]);
    unsigned s1=rfl(rs[r+1]), c1=rfl(degI[r+1]);
    unsigned s2=rfl(rs[r+2]), c2=rfl(degI[r+2]);
    unsigned s3=rfl(rs[r+3]), c3=rfl(degI[r+3]);
    float ax0=0,ay0=0, ax1=0,ay1=0, ax2=0,ay2=0, ax3=0,ay3=0;
    unsigned i0=0,i1=0,i2=0,i3=0;
    while(i0+4<=c0 && i1+4<=c1 && i2+4<=c2 && i3+4<=c3){
        unsigned e00=__builtin_nontemporal_load(&ec[s0+i0]);
        unsigned e01=__builtin_nontemporal_load(&ec[s0+i0+1]);
        unsigned e02=__builtin_nontemporal_load(&ec[s0+i0+2]);
        unsigned e03=__builtin_nontemporal_load(&ec[s0+i0+3]);
        unsigned e10=__builtin_nontemporal_load(&ec[s1+i1]);
        unsigned e11=__builtin_nontemporal_load(&ec[s1+i1+1]);
        unsigned e12=__builtin_nontemporal_load(&ec[s1+i1+2]);
        unsigned e13=__builtin_nontemporal_load(&ec[s1+i1+3]);
        unsigned e20=__builtin_nontemporal_load(&ec[s2+i2]);
        unsigned e21=__builtin_nontemporal_load(&ec[s2+i2+1]);
        unsigned e22=__builtin_nontemporal_load(&ec[s2+i2+2]);
        unsigned e23=__builtin_nontemporal_load(&ec[s2+i2+3]);
        unsigned e30=__builtin_nontemporal_load(&ec[s3+i3]);
        unsigned e31=__builtin_nontemporal_load(&ec[s3+i3+1]);
        unsigned e32=__builtin_nontemporal_load(&ec[s3+i3+2]);
        unsigned e33=__builtin_nontemporal_load(&ec[s3+i3+3]);
        unsigned short u00=hin[(size_t)(e00&0x3FFFFu)*64+lane];
        unsigned short u01=hin[(size_t)(e01&0x3FFFFu)*64+lane];
        unsigned short u02=hin[(size_t)(e02&0x3FFFFu)*64+lane];
        unsigned short u03=hin[(size_t)(e03&0x3FFFFu)*64+lane];
        unsigned short u10=hin[(size_t)(e10&0x3FFFFu)*64+lane];
        unsigned short u11=hin[(size_t)(e11&0x3FFFFu)*64+lane];
        unsigned short u12=hin[(size_t)(e12&0x3FFFFu)*64+lane];
        unsigned short u13=hin[(size_t)(e13&0x3FFFFu)*64+lane];
        unsigned short u20=hin[(size_t)(e20&0x3FFFFu)*64+lane];
        unsigned short u21=hin[(size_t)(e21&0x3FFFFu)*64+lane];
        unsigned short u22=hin[(size_t)(e22&0x3FFFFu)*64+lane];
        unsigned short u23=hin[(size_t)(e23&0x3FFFFu)*64+lane];
        unsigned short u30=hin[(size_t)(e30&0x3FFFFu)*64+lane];
        unsigned short u31=hin[(size_t)(e31&0x3FFFFu)*64+lane];
        unsigned short u32v=hin[(size_t)(e32&0x3FFFFu)*64+lane];
        unsigned short u33=hin[(size_t)(e33&0x3FFFFu)*64+lane];
        v2f v; float w;
        v=fp8x2_to_f32(u00); w=(float)(e00>>18)*(1.f/16383.f); ax0+=w*v.x; ay0+=w*v.y;
        v=fp8x2_to_f32(u01); w=(float)(e01>>18)*(1.f/16383.f); ax0+=w*v.x; ay0+=w*v.y;
        v=fp8x2_to_f32(u02); w=(float)(e02>>18)*(1.f/16383.f); ax0+=w*v.x; ay0+=w*v.y;
        v=fp8x2_to_f32(u03); w=(float)(e03>>18)*(1.f/16383.f); ax0+=w*v.x; ay0+=w*v.y;
        v=fp8x2_to_f32(u10); w=(float)(e10>>18)*(1.f/16383.f); ax1+=w*v.x; ay1+=w*v.y;
        v=fp8x2_to_f32(u11); w=(float)(e11>>18)*(1.f/16383.f); ax1+=w*v.x; ay1+=w*v.y;
        v=fp8x2_to_f32(u12); w=(float)(e12>>18)*(1.f/16383.f); ax1+=w*v.x; ay1+=w*v.y;
        v=fp8x2_to_f32(u13); w=(float)(e13>>18)*(1.f/16383.f); ax1+=w*v.x; ay1+=w*v.y;
        v=fp8x2_to_f32(u20); w=(float)(e20>>18)*(1.f/16383.f); ax2+=w*v.x; ay2+=w*v.y;
        v=fp8x2_to_f32(u21); w=(float)(e21>>18)*(1.f/16383.f); ax2+=w*v.x; ay2+=w*v.y;
        v=fp8x2_to_f32(u22); w=(float)(e22>>18)*(1.f/16383.f); ax2+=w*v.x; ay2+=w*v.y;
        v=fp8x2_to_f32(u23); w=(float)(e23>>18)*(1.f/16383.f); ax2+=w*v.x; ay2+=w*v.y;
        v=fp8x2_to_f32(u30); w=(float)(e30>>18)*(1.f/16383.f); ax3+=w*v.x; ay3+=w*v.y;
        v=fp8x2_to_f32(u31); w=(float)(e31>>18)*(1.f/16383.f); ax3+=w*v.x; ay3+=w*v.y;
        v=fp8x2_to_f32(u32v); w=(float)(e32>>18)*(1.f/16383.f); ax3+=w*v.x; ay3+=w*v.y;
        v=fp8x2_to_f32(u33); w=(float)(e33>>18)*(1.f/16383.f); ax3+=w*v.x; ay3+=w*v.y;
        i0+=4; i1+=4; i2+=4; i3+=4;
    }
    drain_row(hin, ec, s0, c0, i0, lane, ax0, ay0);
    drain_row(hin, ec, s1, c1, i1, lane, ax1, ay1);
    drain_row(hin, ec, s2, c2, i2, lane, ax2, ay2);
    drain_row(hin, ec, s3, c3, i3, lane, ax3, ay3);
    hout[(size_t)(r  )*64+lane] = f32_to_fp8x2(ax0, ay0);
    hout[(size_t)(r+1)*64+lane] = f32_to_fp8x2(ax1, ay1);
    hout[(size_t)(r+2)*64+lane] = f32_to_fp8x2(ax2, ay2);
    hout[(size_t)(r+3)*64+lane] = f32_to_fp8x2(ax3, ay3);
}

// layer-3 SpMM at target-pair slots, fp32 float2 output rows
__global__ __launch_bounds__(256) void k_spmm_t(const unsigned short* __restrict__ hin, float2* __restrict__ h3,
                                                const unsigned* __restrict__ rs, const unsigned* __restrict__ degI,
                                                const unsigned* __restrict__ ec,
                                                const int* __restrict__ user, const int* __restrict__ itp,
                                                const int* __restrict__ itn){
    int wv = (blockIdx.x*256 + threadIdx.x) >> 6;
    int lane = threadIdx.x & 63;
    int t0 = 2*wv, t1 = 2*wv+1;
    if(t0 >= NTGT) return;
    int sec0 = t0>>13, b0 = t0&(BSZ-1);
    int sec1 = t1>>13, b1 = t1&(BSZ-1);
    int n0 = (sec0==0) ? user[b0] : ((sec0==1) ? itp[b0]+N_USER : itn[b0]+N_USER);
    int n1 = (sec1==0) ? user[b1] : ((sec1==1) ? itp[b1]+N_USER : itn[b1]+N_USER);
    n0 = __builtin_amdgcn_readfirstlane(n0);
    n1 = __builtin_amdgcn_readfirstlane(n1);
    unsigned s0 = rfl(rs[n0]), c0 = rfl(degI[n0]);
    unsigned s1 = rfl(rs[n1]), c1 = rfl(degI[n1]);
    float ax0=0.f, ay0=0.f, ax1=0.f, ay1=0.f;
    unsigned i0=0, i1=0;
    while(i0+4<=c0 && i1+4<=c1){
        unsigned e0=ec[s0+i0], e1=ec[s0+i0+1], e2=ec[s0+i0+2], e3=ec[s0+i0+3];
        unsigned e4=ec[s1+i1], e5=ec[s1+i1+1], e6=ec[s1+i1+2], e7=ec[s1+i1+3];
        unsigned short u0=hin[(size_t)(e0&0x3FFFFu)*64+lane];
        unsigned short u1=hin[(size_t)(e1&0x3FFFFu)*64+lane];
        unsigned short u2=hin[(size_t)(e2&0x3FFFFu)*64+lane];
        unsigned short u3=hin[(size_t)(e3&0x3FFFFu)*64+lane];
        unsigned short u4=hin[(size_t)(e4&0x3FFFFu)*64+lane];
        unsigned short u5=hin[(size_t)(e5&0x3FFFFu)*64+lane];
        unsigned short u6=hin[(size_t)(e6&0x3FFFFu)*64+lane];
        unsigned short u7=hin[(size_t)(e7&0x3FFFFu)*64+lane];
        float w0=(float)(e0>>18)*(1.f/16383.f), w1=(float)(e1>>18)*(1.f/16383.f);
        float w2=(float)(e2>>18)*(1.f/16383.f), w3=(float)(e3>>18)*(1.f/16383.f);
        float w4=(float)(e4>>18)*(1.f/16383.f), w5=(float)(e5>>18)*(1.f/16383.f);
        float w6=(float)(e6>>18)*(1.f/16383.f), w7=(float)(e7>>18)*(1.f/16383.f);
        v2f v;
        v=fp8x2_to_f32(u0); ax0+=w0*v.x; ay0+=w0*v.y;
        v=fp8x2_to_f32(u1); ax0+=w1*v.x; ay0+=w1*v.y;
        v=fp8x2_to_f32(u2); ax0+=w2*v.x; ay0+=w2*v.y;
        v=fp8x2_to_f32(u3); ax0+=w3*v.x; ay0+=w3*v.y;
        v=fp8x2_to_f32(u4); ax1+=w4*v.x; ay1+=w4*v.y;
        v=fp8x2_to_f32(u5); ax1+=w5*v.x; ay1+=w5*v.y;
        v=fp8x2_to_f32(u6); ax1+=w6*v.x; ay1+=w6*v.y;
        v=fp8x2_to_f32(u7); ax1+=w7*v.x; ay1+=w7*v.y;
        i0+=4; i1+=4;
    }
    drain_row(hin, ec, s0, c0, i0, lane, ax0, ay0);
    drain_row(hin, ec, s1, c1, i1, lane, ax1, ay1);
    h3[(size_t)t0*64+lane] = make_float2(ax0, ay0);
    h3[(size_t)t1*64+lane] = make_float2(ax1, ay1);
}

// ==== fused gather + score + loss: one wave per sample ===================
__global__ __launch_bounds__(256) void k_scoreloss(const float2* __restrict__ ei, const float2* __restrict__ ep,
                        const unsigned short* __restrict__ h1C, const unsigned short* __restrict__ h2C,
                        const float2* __restrict__ h3,
                        const float* __restrict__ q, const float* __restrict__ bq,
                        const int* __restrict__ user, const int* __restrict__ item_p, const int* __restrict__ item_n,
                        const void* __restrict__ mask, const unsigned* __restrict__ mflag,
                        float4* __restrict__ partial){
    int t = blockIdx.x*256 + threadIdx.x;
    int b = t >> 6, l = t & 63;
    int wv = threadIdx.x >> 6;
    __shared__ float4 wsum[4];
    int nu = user[b];
    int np = item_p[b] + N_USER;
    int nn = item_n[b] + N_USER;

    float2 e0u, e0p, e0n;
    if(l < 32){
        e0u = ei[(size_t)nu*32 + l]; e0p = ei[(size_t)np*32 + l]; e0n = ei[(size_t)nn*32 + l];
    } else {
        e0u = ep[(size_t)nu*32 + (l-32)]; e0p = ep[(size_t)np*32 + (l-32)]; e0n = ep[(size_t)nn*32 + (l-32)];
    }
    v2f h1u = fp8x2_to_f32(h1C[(size_t)nu*64 + l]);
    v2f h1p = fp8x2_to_f32(h1C[(size_t)np*64 + l]);
    v2f h1n = fp8x2_to_f32(h1C[(size_t)nn*64 + l]);
    v2f h2u = fp8x2_to_f32(h2C[(size_t)nu*64 + l]);
    v2f h2p = fp8x2_to_f32(h2C[(size_t)np*64 + l]);
    v2f h2n = fp8x2_to_f32(h2C[(size_t)nn*64 + l]);
    float2 h3u = h3[(size_t)b*64 + l];
    float2 h3p = h3[(size_t)(BSZ   + b)*64 + l];
    float2 h3n = h3[(size_t)(2*BSZ + b)*64 + l];

    float fux = e0u.x + h1u.x + h2u.x + h3u.x, fuy = e0u.y + h1u.y + h2u.y + h3u.y;
    float fpx = e0p.x + h1p.x + h2p.x + h3p.x, fpy = e0p.y + h1p.y + h2p.y + h3p.y;
    float fnx = e0n.x + h1n.x + h2n.x + h3n.x, fny = e0n.y + h1n.y + h2n.y + h3n.y;

    float dp = fux*fpx + fuy*fpy;
    float dn = fux*fnx + fuy*fny;
    for(int off=16; off; off>>=1){ dp += __shfl_down(dp,off,32); dn += __shfl_down(dn,off,32); }
    float pi  = __shfl(dp, 0, 64) * (1.f/16.f);
    float ni  = __shfl(dn, 0, 64) * (1.f/16.f);
    float pp  = __shfl(dp, 32, 64) * (1.f/16.f);
    float npp = __shfl(dn, 32, 64) * (1.f/16.f);
    if(l == 0){
        bool bytes = (*mflag)!=0;
        float mf = bytes ? (((const unsigned char*)mask)[b]?1.f:0.f)
                         : (((const int*)mask)[b]?1.f:0.f);
        float nmf = 1.f-mf;
        float a0 = mf  * logsigf(pi-ni);
        float a1 = mf  * logsigf(npp-pp);
        float a2 = nmf * logsigf(pp-npp);
        int ip=item_p[b], in_=item_n[b];
        float popp = softplusf(q[ip]) + softplusf(bq[ip]);
        float popn = softplusf(q[in_]) + softplusf(bq[in_]);
        float a3 = logsigf(tanhf(popp)*(pi+pp) - tanhf(popn)*(ni+npp));
        wsum[wv] = make_float4(a0,a1,a2,a3);
    }
    __syncthreads();
    if(threadIdx.x == 0){
        float4 s0=wsum[0], s1=wsum[1], s2=wsum[2], s3=wsum[3];
        partial[blockIdx.x] = make_float4(s0.x+s1.x+s2.x+s3.x, s0.y+s1.y+s2.y+s3.y,
                                          s0.z+s1.z+s2.z+s3.z, s0.w+s1.w+s2.w+s3.w);
    }
}

__global__ __launch_bounds__(256) void k_lossfin(const float4* __restrict__ partial, float* __restrict__ out){
    __shared__ float4 sh[256];
    float4 s = make_float4(0,0,0,0);
    for(int i=threadIdx.x; i<LBLK; i+=256){
        float4 v = partial[i];
        s.x+=v.x; s.y+=v.y; s.z+=v.z; s.w+=v.w;
    }
    sh[threadIdx.x]=s;
    __syncthreads();
    for(int off=128; off; off>>=1){
        if(threadIdx.x < off){
            float4 a=sh[threadIdx.x], b2=sh[threadIdx.x+off];
            sh[threadIdx.x]=make_float4(a.x+b2.x,a.y+b2.y,a.z+b2.z,a.w+b2.w);
        }
        __syncthreads();
    }
    if(threadIdx.x==0){
        const float invB = 1.f/(float)BSZ;
        float4 t = sh[0];
        float loss_int  = -t.x*invB;
        float loss_pop  = -t.y*invB + t.z*invB;
        float loss_tide = -t.w*invB;
        out[0] = 0.1f*loss_int + 0.1f*loss_pop + 0.2f*loss_tide;
    }
}

extern "C" void kernel_launch(void* const* d_in, const int* in_sizes, int n_in,
                              void* d_out, int out_size, void* d_ws, size_t ws_size,
                              hipStream_t stream){
    const float* emb_int = (const float*)d_in[0];
    const float* emb_pop = (const float*)d_in[1];
    const float* q    = (const float*)d_in[2];
    const float* bq   = (const float*)d_in[3];
    const int* user   = (const int*)d_in[4];
    const int* item_p = (const int*)d_in[5];
    const int* item_n = (const int*)d_in[6];
    const void* mask  = d_in[7];
    const int* esrc   = (const int*)d_in[8];
    const int* edst   = (const int*)d_in[9];

    char* ws = (char*)d_ws;
    size_t o = 0;
    auto take = [&](size_t bytes)->char*{ char* p = ws + o; o = (o + bytes + 255) & ~(size_t)255; return p; };
    unsigned* histD = (unsigned*)take((size_t)NB*CB*4);
    unsigned* histS = (unsigned*)take((size_t)NB*CB*4);
    unsigned* ctD   = (unsigned*)take((size_t)CB*4);
    unsigned* ctS   = (unsigned*)take((size_t)CB*4);
    unsigned* bsD   = (unsigned*)take((size_t)(CB+1)*4);
    unsigned* bsS   = (unsigned*)take((size_t)(CB+1)*4);
    unsigned* part  = (unsigned*)take((size_t)NEDGE*4);
    unsigned char* spart = (unsigned char*)take((size_t)NEDGE);
    float*    rsqO  = (float*)take((size_t)NNODE*4);
    unsigned* degI  = (unsigned*)take((size_t)NNODE*4);
    unsigned* rs    = (unsigned*)take((size_t)NNODE*4);
    unsigned* ec    = (unsigned*)take((size_t)NEDGE*4);
    unsigned short* hE  = (unsigned short*)take((size_t)NNODE*64*2);
    unsigned short* h1C = (unsigned short*)take((size_t)NNODE*64*2);
    unsigned short* h2C = (unsigned short*)take((size_t)NNODE*64*2);
    float2*   h3    = (float2*)take((size_t)NTGT*64*8);
    float4*   partial = (float4*)take((size_t)LBLK*16);
    unsigned* mflag = (unsigned*)take(256);
    (void)ws_size; (void)in_sizes; (void)n_in; (void)out_size;

    // fused: coarse hist ([chunk][bin]) + fp8 prep + mask detect
    k_hist<<<NB + PREPB + 1,256,0,stream>>>(esrc, edst, histD, histS,
                                            (const float2*)emb_int, (const float2*)emb_pop,
                                            (unsigned*)hE, (const unsigned char*)mask, mflag);
    k_colscan<<<dim3(CB,2),512,0,stream>>>(histD, histS, ctD, ctS);
    k_bstart<<<1,1024,0,stream>>>(ctD, ctS, bsD, bsS);
    k_scatter<<<NB,256,0,stream>>>(esrc, edst, histD, histS, bsD, bsS, part, spart);
    k_degO<<<CB,256,0,stream>>>(spart, bsS, rsqO);
    k_csr<<<CB,256,0,stream>>>(part, bsD, rsqO, rs, degI, ec);

    const int spB = ((NNODE/4)*64 + 255)/256;     // one wave per 4 rows
    k_spmm_c<<<spB,256,0,stream>>>(hE,  h1C, rs, degI, ec);  // layer 1
    k_spmm_c<<<spB,256,0,stream>>>(h1C, h2C, rs, degI, ec);  // layer 2
    k_spmm_t<<<((NTGT/2)*64 + 255)/256,256,0,stream>>>(h2C, h3, rs, degI, ec,
                                                 user, item_p, item_n);                  // layer 3
    k_scoreloss<<<LBLK,256,0,stream>>>((const float2*)emb_int, (const float2*)emb_pop,
                                       h1C, h2C, h3, q, bq, user, item_p, item_n,
                                       mask, mflag, partial);
    k_lossfin<<<1,256,0,stream>>>(partial, (float*)d_out);
}